// Round 4
// baseline (489.877 us; speedup 1.0000x reference)
//
#include <hip/hip_runtime.h>

#define HW 16384
#define CIN 512
#define PL 256
#define EPSF 1e-5f
#define SLO 0.0009765625f   // 2^-10
#define NSTEP 16            // K-steps per chunk (BK=64 floats, chunk=1024)

using half8  = __attribute__((ext_vector_type(8))) _Float16;
using half4v = __attribute__((ext_vector_type(4))) _Float16;
using f32x4  = __attribute__((ext_vector_type(4))) float;

__device__ inline half8 cvt_hi8(float4 a, float4 b) {
  half8 h;
  h[0] = (_Float16)a.x; h[1] = (_Float16)a.y; h[2] = (_Float16)a.z; h[3] = (_Float16)a.w;
  h[4] = (_Float16)b.x; h[5] = (_Float16)b.y; h[6] = (_Float16)b.z; h[7] = (_Float16)b.w;
  return h;
}
__device__ inline half8 cvt_lo8(float4 a, float4 b, half8 hi) {
  half8 l;
  l[0] = (_Float16)((a.x - (float)hi[0]) * 1024.f);
  l[1] = (_Float16)((a.y - (float)hi[1]) * 1024.f);
  l[2] = (_Float16)((a.z - (float)hi[2]) * 1024.f);
  l[3] = (_Float16)((a.w - (float)hi[3]) * 1024.f);
  l[4] = (_Float16)((b.x - (float)hi[4]) * 1024.f);
  l[5] = (_Float16)((b.y - (float)hi[5]) * 1024.f);
  l[6] = (_Float16)((b.z - (float)hi[6]) * 1024.f);
  l[7] = (_Float16)((b.w - (float)hi[7]) * 1024.f);
  return l;
}

// ---------- kernel 0a: Wt f32 -> f16
__global__ __launch_bounds__(256) void k_wcvt(const float* __restrict__ Wt,
                                              _Float16* __restrict__ Wh) {
  int idx = blockIdx.x * 256 + threadIdx.x;   // < 256*512
  Wh[idx] = (_Float16)Wt[idx];
}

// ---------- kernel 0b: x [b][c][hw] f32 -> xT [b][hw][c] f16 hi; also xsum[b][c] (atomic)
__global__ __launch_bounds__(256) void k_xpose(const float* __restrict__ x,
                                               _Float16* __restrict__ xT,
                                               float* __restrict__ xsum) {
  __shared__ float lds[64 * 65];
  int b = blockIdx.z;
  int cb = blockIdx.y << 6;
  int nb = blockIdx.x << 6;
  int tid = threadIdx.x;
  int q = tid & 15;
  int p = tid >> 4;
  const float* xb = x + ((size_t)b * CIN + cb) * HW + nb;
#pragma unroll
  for (int i = 0; i < 4; ++i) {
    int c = p + i * 16;
    float4 v = *reinterpret_cast<const float4*>(xb + (size_t)c * HW + (q << 2));
    lds[c * 65 + (q << 2) + 0] = v.x;
    lds[c * 65 + (q << 2) + 1] = v.y;
    lds[c * 65 + (q << 2) + 2] = v.z;
    lds[c * 65 + (q << 2) + 3] = v.w;
    float s = v.x + v.y + v.z + v.w;
    s += __shfl_xor(s, 1); s += __shfl_xor(s, 2);
    s += __shfl_xor(s, 4); s += __shfl_xor(s, 8);
    if (q == 0) atomicAdd(xsum + b * CIN + cb + c, s);
  }
  __syncthreads();
  size_t obase = ((size_t)b * HW + nb) * CIN + cb;
#pragma unroll
  for (int i = 0; i < 4; ++i) {
    int n = p + i * 16;
    half4v h;
#pragma unroll
    for (int j = 0; j < 4; ++j) h[j] = (_Float16)lds[(q * 4 + j) * 65 + n];
    *reinterpret_cast<half4v*>(xT + obase + (size_t)n * CIN + (q << 2)) = h;
  }
}

// ---------- kernel 1: t GEMM (hi only) -> t_ws fp16 [b][o][hw]
__global__ __launch_bounds__(512) void k_t(const _Float16* __restrict__ xT,
                                           const _Float16* __restrict__ Wh,
                                           _Float16* __restrict__ t_ws) {
  int tid = threadIdx.x;
  int wave = tid >> 6, lane = tid & 63;
  int l15 = lane & 15, l4 = lane >> 4;
  int b = blockIdx.y;
  int nb = blockIdx.x << 6;
  const _Float16* xTb = xT + (size_t)b * HW * CIN;

  const half8* ap[4];
#pragma unroll
  for (int nf = 0; nf < 4; ++nf)
    ap[nf] = reinterpret_cast<const half8*>(xTb + (size_t)(nb + nf * 16 + l15) * CIN + l4 * 8);
  const half8* bp[2];
#pragma unroll
  for (int ob = 0; ob < 2; ++ob) {
    int row = wave * 32 + ob * 16 + l15;
    bp[ob] = reinterpret_cast<const half8*>(Wh + (size_t)row * CIN + l4 * 8);
  }

  f32x4 acc[2][4];
#pragma unroll
  for (int ob = 0; ob < 2; ++ob)
#pragma unroll
    for (int nf = 0; nf < 4; ++nf) acc[ob][nf] = f32x4{0.f, 0.f, 0.f, 0.f};

#pragma unroll
  for (int ks = 0; ks < 16; ++ks) {
    half8 af[4], bf[2];
#pragma unroll
    for (int nf = 0; nf < 4; ++nf) af[nf] = ap[nf][ks * 4];
#pragma unroll
    for (int ob = 0; ob < 2; ++ob) bf[ob] = bp[ob][ks * 4];
#pragma unroll
    for (int ob = 0; ob < 2; ++ob)
#pragma unroll
      for (int nf = 0; nf < 4; ++nf)
        acc[ob][nf] = __builtin_amdgcn_mfma_f32_16x16x32_f16(af[nf], bf[ob], acc[ob][nf], 0, 0, 0);
  }

  __shared__ _Float16 tl[256 * 72];
#pragma unroll
  for (int ob = 0; ob < 2; ++ob)
#pragma unroll
    for (int nf = 0; nf < 4; ++nf)
#pragma unroll
      for (int r = 0; r < 4; ++r) {
        int o_l = wave * 32 + ob * 16 + l15;
        int n_l = nf * 16 + l4 * 4 + r;
        tl[o_l * 72 + n_l] = (_Float16)acc[ob][nf][r];
      }
  __syncthreads();
  _Float16* tb = t_ws + (((size_t)b * PL) << 14) + nb;
  for (int idx = tid; idx < 256 * 16; idx += 512) {
    int row = idx >> 4, seg = idx & 15;
    *reinterpret_cast<uint2*>(tb + (size_t)row * HW + (seg << 2)) =
        *reinterpret_cast<const uint2*>(&tl[row * 72 + (seg << 2)]);
  }
}

// ---------- kernel 2: symmetric Gram, upper 128x128 tiles only, 3 MFMA chains, dbuf pipeline.
// GH[i][j]=Xh_i.Xh_j ; C1[i][j]=Xl_i.Xh_j ; C2[i][j]=Xh_i.Xl_j  (i-tile >= j-tile)
__global__ __launch_bounds__(512) void k_gram(const float* __restrict__ x,
                                              float* __restrict__ GH,
                                              float* __restrict__ C1,
                                              float* __restrict__ C2) {
  __shared__ char ldsraw[2 * 4 * 16384];   // [dbuf][Ah,Al,Bh,Bl][128 rows x 128 B]
  int t = blockIdx.x;                      // 0..9 upper-tile id
  int ti = 0;
  while ((ti + 1) * (ti + 2) / 2 <= t) ++ti;
  int tj = t - ti * (ti + 1) / 2;
  bool diag = (ti == tj);
  int ks = blockIdx.y, b = blockIdx.z;
  int i0 = ti << 7, j0 = tj << 7;
  const float* xb = x + (size_t)b * CIN * HW;
  int tid = threadIdx.x;
  int wave = tid >> 6, lane = tid & 63, l15 = lane & 15, l4 = lane >> 4;
  int wr = wave >> 2, wc = wave & 3;
  int srow = tid >> 2, sseg = tid & 3;
  int ksbase = ks << 10;

  const float* pA = xb + (size_t)(i0 + srow) * HW + ksbase + sseg * 16;
  const float* pB = xb + (size_t)(j0 + srow) * HW + ksbase + sseg * 16;

  f32x4 aH[4][2], a1[4][2], a2[4][2];
#pragma unroll
  for (int rf = 0; rf < 4; ++rf)
#pragma unroll
    for (int cf = 0; cf < 2; ++cf) {
      aH[rf][cf] = f32x4{0.f, 0.f, 0.f, 0.f};
      a1[rf][cf] = f32x4{0.f, 0.f, 0.f, 0.f};
      a2[rf][cf] = f32x4{0.f, 0.f, 0.f, 0.f};
    }

  int swz = (srow & 7) << 4;
  int wa0 = srow * 128 + ((sseg * 32) ^ swz);
  int wa1 = srow * 128 + ((sseg * 32 + 16) ^ swz);

  // precompute frag byte-addresses (within a panel)
  int adA[4][2], adB[2][2];
#pragma unroll
  for (int rf = 0; rf < 4; ++rf) {
    int rl = wr * 64 + rf * 16 + l15;
#pragma unroll
    for (int ksub = 0; ksub < 2; ++ksub) {
      int kb = ksub * 64 + l4 * 16;
      adA[rf][ksub] = rl * 128 + (kb ^ ((rl & 7) << 4));
    }
  }
#pragma unroll
  for (int cf = 0; cf < 2; ++cf) {
    int cl = wc * 32 + cf * 16 + l15;
#pragma unroll
    for (int ksub = 0; ksub < 2; ++ksub) {
      int kb = ksub * 64 + l4 * 16;
      adB[cf][ksub] = cl * 128 + (kb ^ ((cl & 7) << 4));
    }
  }
  int pB_hi = diag ? 0 : 2, pB_lo = diag ? 1 : 3;

  float4 va[4], vb4[4];
#pragma unroll
  for (int u = 0; u < 4; ++u) va[u] = *reinterpret_cast<const float4*>(pA + u * 4);
  if (!diag) {
#pragma unroll
    for (int u = 0; u < 4; ++u) vb4[u] = *reinterpret_cast<const float4*>(pB + u * 4);
  }
  // prologue stage -> buf0
  {
    char* base = ldsraw;
    half8 h0 = cvt_hi8(va[0], va[1]), h1 = cvt_hi8(va[2], va[3]);
    *reinterpret_cast<half8*>(base + wa0) = h0;
    *reinterpret_cast<half8*>(base + wa1) = h1;
    *reinterpret_cast<half8*>(base + 16384 + wa0) = cvt_lo8(va[0], va[1], h0);
    *reinterpret_cast<half8*>(base + 16384 + wa1) = cvt_lo8(va[2], va[3], h1);
    if (!diag) {
      half8 g0 = cvt_hi8(vb4[0], vb4[1]), g1 = cvt_hi8(vb4[2], vb4[3]);
      *reinterpret_cast<half8*>(base + 32768 + wa0) = g0;
      *reinterpret_cast<half8*>(base + 32768 + wa1) = g1;
      *reinterpret_cast<half8*>(base + 49152 + wa0) = cvt_lo8(vb4[0], vb4[1], g0);
      *reinterpret_cast<half8*>(base + 49152 + wa1) = cvt_lo8(vb4[2], vb4[3], g1);
    }
  }
  __syncthreads();

  for (int s = 0; s < NSTEP; ++s) {
    // prefetch next step into registers (overlaps the MFMA section below)
    if (s + 1 < NSTEP) {
      const float* nA = pA + (s + 1) * 64;
#pragma unroll
      for (int u = 0; u < 4; ++u) va[u] = *reinterpret_cast<const float4*>(nA + u * 4);
      if (!diag) {
        const float* nB = pB + (s + 1) * 64;
#pragma unroll
        for (int u = 0; u < 4; ++u) vb4[u] = *reinterpret_cast<const float4*>(nB + u * 4);
      }
    }
    // MFMA on current buffer
    char* cbase = ldsraw + ((s & 1) << 16);
#pragma unroll
    for (int ksub = 0; ksub < 2; ++ksub) {
      half8 ah[4], al[4], bh[2], bl[2];
#pragma unroll
      for (int rf = 0; rf < 4; ++rf) {
        ah[rf] = *reinterpret_cast<const half8*>(cbase + adA[rf][ksub]);
        al[rf] = *reinterpret_cast<const half8*>(cbase + 16384 + adA[rf][ksub]);
      }
#pragma unroll
      for (int cf = 0; cf < 2; ++cf) {
        bh[cf] = *reinterpret_cast<const half8*>(cbase + pB_hi * 16384 + adB[cf][ksub]);
        bl[cf] = *reinterpret_cast<const half8*>(cbase + pB_lo * 16384 + adB[cf][ksub]);
      }
#pragma unroll
      for (int rf = 0; rf < 4; ++rf)
#pragma unroll
        for (int cf = 0; cf < 2; ++cf) {
          aH[rf][cf] = __builtin_amdgcn_mfma_f32_16x16x32_f16(ah[rf], bh[cf], aH[rf][cf], 0, 0, 0);
          a1[rf][cf] = __builtin_amdgcn_mfma_f32_16x16x32_f16(al[rf], bh[cf], a1[rf][cf], 0, 0, 0);
          a2[rf][cf] = __builtin_amdgcn_mfma_f32_16x16x32_f16(ah[rf], bl[cf], a2[rf][cf], 0, 0, 0);
        }
    }
    // stage next step into the other buffer
    if (s + 1 < NSTEP) {
      char* nbase = ldsraw + (((s + 1) & 1) << 16);
      half8 h0 = cvt_hi8(va[0], va[1]), h1 = cvt_hi8(va[2], va[3]);
      *reinterpret_cast<half8*>(nbase + wa0) = h0;
      *reinterpret_cast<half8*>(nbase + wa1) = h1;
      *reinterpret_cast<half8*>(nbase + 16384 + wa0) = cvt_lo8(va[0], va[1], h0);
      *reinterpret_cast<half8*>(nbase + 16384 + wa1) = cvt_lo8(va[2], va[3], h1);
      if (!diag) {
        half8 g0 = cvt_hi8(vb4[0], vb4[1]), g1 = cvt_hi8(vb4[2], vb4[3]);
        *reinterpret_cast<half8*>(nbase + 32768 + wa0) = g0;
        *reinterpret_cast<half8*>(nbase + 32768 + wa1) = g1;
        *reinterpret_cast<half8*>(nbase + 49152 + wa0) = cvt_lo8(vb4[0], vb4[1], g0);
        *reinterpret_cast<half8*>(nbase + 49152 + wa1) = cvt_lo8(vb4[2], vb4[3], g1);
      }
      __syncthreads();
    }
  }

  size_t bo = (size_t)b << 18;
#pragma unroll
  for (int rf = 0; rf < 4; ++rf)
#pragma unroll
    for (int cf = 0; cf < 2; ++cf)
#pragma unroll
      for (int r = 0; r < 4; ++r) {
        int i = i0 + wr * 64 + rf * 16 + l4 * 4 + r;
        int j = j0 + wc * 32 + cf * 16 + l15;
        size_t off = bo + ((size_t)i << 9) + j;
        atomicAdd(GH + off, aH[rf][cf][r]);
        atomicAdd(C1 + off, a1[rf][cf][r]);
        atomicAdd(C2 + off, a2[rf][cf][r]);
      }
}

// ---------- kernel 3: Gs full symmetric matrix from upper-tile GH/C1/C2
__global__ __launch_bounds__(256) void k_sym(const float* __restrict__ GH,
                                             const float* __restrict__ C1,
                                             const float* __restrict__ C2,
                                             float* __restrict__ Gs) {
  __shared__ float T[64 * 65];
  int I = blockIdx.x, J = blockIdx.y, b = blockIdx.z;
  int i0 = I << 6, j0 = J << 6;
  size_t bo = (size_t)b << 18;
  int tid = threadIdx.x;
  int r = tid >> 2, cs = (tid & 3) << 4;
  if ((I >> 1) >= (J >> 1)) {
    // data exists at [i][j]
#pragma unroll
    for (int u = 0; u < 16; u += 4) {
      size_t off = bo + (((size_t)(i0 + r)) << 9) + j0 + cs + u;
      float4 h = *reinterpret_cast<const float4*>(GH + off);
      float4 c1 = *reinterpret_cast<const float4*>(C1 + off);
      float4 c2 = *reinterpret_cast<const float4*>(C2 + off);
      float4 o;
      o.x = h.x + SLO * (c1.x + c2.x);
      o.y = h.y + SLO * (c1.y + c2.y);
      o.z = h.z + SLO * (c1.z + c2.z);
      o.w = h.w + SLO * (c1.w + c2.w);
      *reinterpret_cast<float4*>(Gs + off) = o;
    }
  } else {
    // mirror: Gs[i][j] = val[j][i]; stage source tile rows, write transposed
#pragma unroll
    for (int u = 0; u < 16; u += 4) {
      size_t off = bo + (((size_t)(j0 + r)) << 9) + i0 + cs + u;
      float4 h = *reinterpret_cast<const float4*>(GH + off);
      float4 c1 = *reinterpret_cast<const float4*>(C1 + off);
      float4 c2 = *reinterpret_cast<const float4*>(C2 + off);
      T[r * 65 + cs + u + 0] = h.x + SLO * (c1.x + c2.x);
      T[r * 65 + cs + u + 1] = h.y + SLO * (c1.y + c2.y);
      T[r * 65 + cs + u + 2] = h.z + SLO * (c1.z + c2.z);
      T[r * 65 + cs + u + 3] = h.w + SLO * (c1.w + c2.w);
    }
    __syncthreads();
#pragma unroll
    for (int u = 0; u < 16; u += 4) {
      size_t off = bo + (((size_t)(i0 + r)) << 9) + j0 + cs + u;
      float4 o;
      o.x = T[(cs + u + 0) * 65 + r];
      o.y = T[(cs + u + 1) * 65 + r];
      o.z = T[(cs + u + 2) * 65 + r];
      o.w = T[(cs + u + 3) * 65 + r];
      *reinterpret_cast<float4*>(Gs + off) = o;
    }
  }
}

// ---------- kernel 4: V[b][ocol][i] = sum_j W[ocol][j] * Gs[b][i][j]   (ocol<256: Wg, else Wt)
__global__ __launch_bounds__(256) void k_V(const float* __restrict__ Gs,
                                           const float* __restrict__ Wg,
                                           const float* __restrict__ Wt,
                                           float* __restrict__ V) {
  __shared__ float Gl[64 * 65];
  __shared__ float Wl[64 * 65];
  int it = blockIdx.x, ot = blockIdx.y, b = blockIdx.z;
  int i0 = it << 6, o0 = ot << 6;
  int tid = threadIdx.x;
  int srow = tid >> 2, sseg = (tid & 3) << 4;
  const float* gsb = Gs + ((size_t)b << 18);
  int orow = o0 + srow;
  const float* wrow = (orow < 256) ? (Wg + (size_t)orow * 512) : (Wt + (size_t)(orow - 256) * 512);
  float acc[4][4];
#pragma unroll
  for (int a = 0; a < 4; ++a)
#pragma unroll
    for (int c = 0; c < 4; ++c) acc[a][c] = 0.f;
  int oy = (tid >> 4) << 2, ix = (tid & 15) << 2;
  for (int jc = 0; jc < 512; jc += 64) {
    __syncthreads();
#pragma unroll
    for (int u = 0; u < 16; u += 4) {
      float4 g = *reinterpret_cast<const float4*>(gsb + ((size_t)(i0 + srow) << 9) + jc + sseg + u);
      float4 w = *reinterpret_cast<const float4*>(wrow + jc + sseg + u);
      Gl[srow * 65 + sseg + u + 0] = g.x; Gl[srow * 65 + sseg + u + 1] = g.y;
      Gl[srow * 65 + sseg + u + 2] = g.z; Gl[srow * 65 + sseg + u + 3] = g.w;
      Wl[srow * 65 + sseg + u + 0] = w.x; Wl[srow * 65 + sseg + u + 1] = w.y;
      Wl[srow * 65 + sseg + u + 2] = w.z; Wl[srow * 65 + sseg + u + 3] = w.w;
    }
    __syncthreads();
    for (int j = 0; j < 64; ++j) {
      float w0 = Wl[(oy + 0) * 65 + j], w1 = Wl[(oy + 1) * 65 + j];
      float w2 = Wl[(oy + 2) * 65 + j], w3 = Wl[(oy + 3) * 65 + j];
      float g0 = Gl[(ix + 0) * 65 + j], g1 = Gl[(ix + 1) * 65 + j];
      float g2 = Gl[(ix + 2) * 65 + j], g3 = Gl[(ix + 3) * 65 + j];
      acc[0][0] += w0 * g0; acc[0][1] += w0 * g1; acc[0][2] += w0 * g2; acc[0][3] += w0 * g3;
      acc[1][0] += w1 * g0; acc[1][1] += w1 * g1; acc[1][2] += w1 * g2; acc[1][3] += w1 * g3;
      acc[2][0] += w2 * g0; acc[2][1] += w2 * g1; acc[2][2] += w2 * g2; acc[2][3] += w2 * g3;
      acc[3][0] += w3 * g0; acc[3][1] += w3 * g1; acc[3][2] += w3 * g2; acc[3][3] += w3 * g3;
    }
  }
  float* vb = V + ((size_t)b << 18);
#pragma unroll
  for (int a = 0; a < 4; ++a) {
    float4 vv = {acc[a][0], acc[a][1], acc[a][2], acc[a][3]};
    *reinterpret_cast<float4*>(vb + ((size_t)(o0 + oy + a) << 9) + i0 + ix) = vv;
  }
}

// ---------- kernel 5: att/tsq/tsum per (b,o)
__global__ __launch_bounds__(256) void k_red2(const float* __restrict__ V,
                                              const float* __restrict__ xsum,
                                              const float* __restrict__ Wp,
                                              const float* __restrict__ Wt,
                                              float* __restrict__ att,
                                              float* __restrict__ tsum,
                                              float* __restrict__ tsq) {
  int b = blockIdx.x, o = threadIdx.x;
  const float* vg = V + ((size_t)b << 18) + ((size_t)o << 9);
  const float* vt = V + ((size_t)b << 18) + ((size_t)(256 + o) << 9);
  const float* wp = Wp + (size_t)o * 512;
  const float* wt = Wt + (size_t)o * 512;
  const float* xs = xsum + b * CIN;
  float sa = 0.f, sq = 0.f, sm = 0.f;
  for (int i = 0; i < 512; i += 4) {
    float4 a = *reinterpret_cast<const float4*>(vg + i);
    float4 p = *reinterpret_cast<const float4*>(wp + i);
    float4 c = *reinterpret_cast<const float4*>(vt + i);
    float4 t = *reinterpret_cast<const float4*>(wt + i);
    float4 s = *reinterpret_cast<const float4*>(xs + i);
    sa += a.x * p.x + a.y * p.y + a.z * p.z + a.w * p.w;
    sq += c.x * t.x + c.y * t.y + c.z * t.z + c.w * t.w;
    sm += t.x * s.x + t.y * s.y + t.z * s.z + t.w * s.w;
  }
  att[b * PL + o] = sa;
  tsq[b * PL + o] = sq;
  tsum[b * PL + o] = sm;
}

// ---------- kernel 6: graph math (one block, 1024 threads)
__global__ __launch_bounds__(1024) void k_graph(
    const float* __restrict__ att, const float* __restrict__ tsum, const float* __restrict__ tsq,
    const float* __restrict__ W_adj, const float* __restrict__ bnag, const float* __restrict__ bnab,
    const float* __restrict__ bnam, const float* __restrict__ bnav,
    const float* __restrict__ W_wg, const float* __restrict__ bwgg, const float* __restrict__ bwgb,
    const float* __restrict__ bwgm, const float* __restrict__ bwgv,
    const float* __restrict__ Wz, const float* __restrict__ gng, const float* __restrict__ gnb,
    float* __restrict__ sA, float* __restrict__ sB) {
  __shared__ float att_l[4 * 256];
  __shared__ float z_l[4 * 256];
  __shared__ float zv_l[4 * 256];
  int tid = threadIdx.x;
  att_l[tid] = att[tid];
  __syncthreads();
  int b = tid >> 8, r = tid & 255, i = r >> 3, k = r & 7;
  float z1 = 0.f;
#pragma unroll
  for (int m = 0; m < 32; ++m) z1 += W_adj[i * 32 + m] * att_l[b * 256 + k * 32 + m];
  float inv = rsqrtf(bnav[i] + EPSF);
  float z = (z1 - bnam[i]) * inv * bnag[i] + bnab[i];
  z = fmaxf(z, 0.f) + att_l[b * 256 + k * 32 + i];
  z_l[b * 256 + i * 8 + k] = z;
  __syncthreads();
  float z2 = 0.f;
#pragma unroll
  for (int e = 0; e < 8; ++e) z2 += W_wg[k * 8 + e] * z_l[b * 256 + i * 8 + e];
  float inv2 = rsqrtf(bwgv[k] + EPSF);
  z2 = (z2 - bwgm[k]) * inv2 * bwgg[k] + bwgb[k];
  zv_l[b * 256 + i * 8 + k] = fmaxf(z2, 0.f);
  __syncthreads();
  int g = r;
  float s = zv_l[b * 256 + g];
  float m1 = tsum[b * 256 + g] * (1.f / 16384.f);
  float m2 = tsq[b * 256 + g] * (1.f / 16384.f);
  float a0 = Wz[2 * g] * s, a1 = Wz[2 * g + 1] * s;
  float mu = 0.5f * (a0 + a1) * m1;
  float ey2 = 0.5f * (a0 * a0 + a1 * a1) * m2;
  float var = ey2 - mu * mu;
  float invg = rsqrtf(var + EPSF);
  int c = b * CIN + 2 * g;
  sA[c]     = a0 * invg * gng[2 * g];
  sA[c + 1] = a1 * invg * gng[2 * g + 1];
  sB[c]     = gnb[2 * g]     - mu * invg * gng[2 * g];
  sB[c + 1] = gnb[2 * g + 1] - mu * invg * gng[2 * g + 1];
}

// ---------- kernel 7: out = sA*t + sB + x
__global__ __launch_bounds__(256) void k_out(const _Float16* __restrict__ t_ws,
                                             const float* __restrict__ x,
                                             const float* __restrict__ sA,
                                             const float* __restrict__ sB,
                                             float* __restrict__ out) {
  int blk = blockIdx.x;                 // 16384 = 4b * 256g * 16
  int b = blk >> 12;
  int g = (blk >> 4) & 255;
  int hw0 = (((blk & 15) << 8) + threadIdx.x) << 2;
  half4v tv = *reinterpret_cast<const half4v*>(t_ws + (((size_t)(b * PL + g)) << 14) + hw0);
  size_t xoff = (((size_t)(b * CIN + 2 * g)) << 14) + hw0;
  float4 x0 = *reinterpret_cast<const float4*>(x + xoff);
  float4 x1 = *reinterpret_cast<const float4*>(x + xoff + HW);
  int c = b * CIN + 2 * g;
  float s0 = sA[c], s1 = sA[c + 1], b0 = sB[c], b1 = sB[c + 1];
  float t0 = (float)tv[0], t1 = (float)tv[1], t2 = (float)tv[2], t3 = (float)tv[3];
  float4 o0, o1;
  o0.x = fmaf(s0, t0, x0.x + b0); o0.y = fmaf(s0, t1, x0.y + b0);
  o0.z = fmaf(s0, t2, x0.z + b0); o0.w = fmaf(s0, t3, x0.w + b0);
  o1.x = fmaf(s1, t0, x1.x + b1); o1.y = fmaf(s1, t1, x1.y + b1);
  o1.z = fmaf(s1, t2, x1.z + b1); o1.w = fmaf(s1, t3, x1.w + b1);
  *reinterpret_cast<float4*>(out + xoff) = o0;
  *reinterpret_cast<float4*>(out + xoff + HW) = o1;
}

// ---------- launch
extern "C" void kernel_launch(void* const* d_in, const int* in_sizes, int n_in,
                              void* d_out, int out_size, void* d_ws, size_t ws_size,
                              hipStream_t stream) {
  const float* x    = (const float*)d_in[0];
  const float* Wt   = (const float*)d_in[1];
  const float* Wp   = (const float*)d_in[2];
  const float* Wg   = (const float*)d_in[3];
  const float* Wz   = (const float*)d_in[4];
  const float* Wadj = (const float*)d_in[5];
  const float* bnag = (const float*)d_in[6];
  const float* bnab = (const float*)d_in[7];
  const float* bnam = (const float*)d_in[8];
  const float* bnav = (const float*)d_in[9];
  const float* Wwg  = (const float*)d_in[10];
  const float* bwgg = (const float*)d_in[11];
  const float* bwgb = (const float*)d_in[12];
  const float* bwgm = (const float*)d_in[13];
  const float* bwgv = (const float*)d_in[14];
  const float* gng  = (const float*)d_in[15];
  const float* gnb  = (const float*)d_in[16];

  char* ws = (char*)d_ws;
  _Float16* xT   = (_Float16*)(ws);                    // 67108864
  _Float16* Wh   = (_Float16*)(ws + 67108864);         // 262144
  _Float16* t_ws = (_Float16*)(ws + 67371008);         // 33554432
  float* xsum = (float*)(ws + 100925440);              // 8192
  float* att  = (float*)(ws + 100933632);              // 4096
  float* tsum = (float*)(ws + 100937728);              // 4096
  float* tsq  = (float*)(ws + 100941824);              // 4096
  float* sA   = (float*)(ws + 100945920);              // 8192
  float* sB   = (float*)(ws + 100954112);              // 8192
  if (ws_size < (size_t)100962304) return;

  // Gram buffers live in d_out (overwritten by k_out at the end)
  float* GH = (float*)((char*)d_out);                  // 4194304
  float* C1 = (float*)((char*)d_out + 4194304);        // 4194304
  float* C2 = (float*)((char*)d_out + 8388608);        // 4194304
  float* Gs = (float*)((char*)d_out + 12582912);       // 4194304
  float* V  = (float*)((char*)d_out + 16777216);       // 4194304
  float* out = (float*)d_out;

  hipMemsetAsync(d_out, 0, 12582912, stream);          // GH, C1, C2
  hipMemsetAsync(xsum, 0, 8192, stream);
  k_wcvt<<<dim3(512), dim3(256), 0, stream>>>(Wt, Wh);
  k_xpose<<<dim3(256, 8, 4), dim3(256), 0, stream>>>(x, xT, xsum);
  k_t<<<dim3(256, 4), dim3(512), 0, stream>>>(xT, Wh, t_ws);
  k_gram<<<dim3(10, 16, 4), dim3(512), 0, stream>>>(x, GH, C1, C2);
  k_sym<<<dim3(8, 8, 4), dim3(256), 0, stream>>>(GH, C1, C2, Gs);
  k_V<<<dim3(8, 8, 4), dim3(256), 0, stream>>>(Gs, Wg, Wt, V);
  k_red2<<<dim3(4), dim3(256), 0, stream>>>(V, xsum, Wp, Wt, att, tsum, tsq);
  k_graph<<<dim3(1), dim3(1024), 0, stream>>>(att, tsum, tsq, Wadj, bnag, bnab, bnam, bnav,
                                              Wwg, bwgg, bwgb, bwgm, bwgv, Wz, gng, gnb, sA, sB);
  k_out<<<dim3(16384), dim3(256), 0, stream>>>(t_ws, x, sA, sB, out);
}